// Round 1
// baseline (705.449 us; speedup 1.0000x reference)
//
#include <hip/hip_runtime.h>
#include <math.h>

#define DEV_INLINE __device__ __forceinline__

constexpr int Nn = 256;
constexpr size_t SZW = (size_t)16 * 256 * 256 * 16;  // 16,777,216
constexpr size_t SZB = (size_t)16 * 256 * 16;        // 65,536
constexpr size_t OSTRIDE = SZW + SZB;                // per-layer output stride

// workspace layout (float offsets)
constexpr int T_GT = 0;          // global_terms [4][4][4][256]  = 16384
constexpr int T_DT = 16384;      // diag_terms   [6][4][256]     = 6144
constexpr int T_P1 = 22528;      // diag_p1      [2][3][256]     = 1536
constexpr int T_M1 = 24064;      // diag_m1      [2][3][256]     = 1536
constexpr int O_RS = 25600;      // rsum_raw [4][16][256][16]    = 262144
constexpr int O_CS = 287744;     // csum_raw                      = 262144
constexpr int O_AS = 549888;     // allsum_raw [4][16][16]        = 1024
constexpr int O_BS = 550912;     // bsum_raw   [4][16][16]        = 1024
constexpr int O_AROW = 551936;   // Arow [4][16][256][16]         = 262144
constexpr int O_BCOL = 814080;   // Bcol                          = 262144

DEV_INLINE void f4acc(float4& a, const float4 b) { a.x += b.x; a.y += b.y; a.z += b.z; a.w += b.w; }
DEV_INLINE float4 f4add(const float4 a, const float4 b) { return make_float4(a.x + b.x, a.y + b.y, a.z + b.z, a.w + b.w); }
DEV_INLINE void f4fma(float4& a, float s, const float4 t) {
    a.x = fmaf(s, t.x, a.x); a.y = fmaf(s, t.y, a.y);
    a.z = fmaf(s, t.z, a.z); a.w = fmaf(s, t.w, a.w);
}

// ---------------- SIREN: 100 points through 3->64->64->64->256 ----------------
__global__ __launch_bounds__(64) void siren_kernel(
    const float* __restrict__ sw0, const float* __restrict__ sb0,
    const float* __restrict__ sw1, const float* __restrict__ sb1,
    const float* __restrict__ sw2, const float* __restrict__ sb2,
    const float* __restrict__ swo, const float* __restrict__ sbo,
    float* __restrict__ ws) {
    __shared__ float h[64];
    const int p = blockIdx.x, t = threadIdx.x;
    const float lv[4] = {-1.f, -1.f / 3.f, 1.f / 3.f, 1.f};
    float x, y, tt;
    if (p < 64)      { int tm = p >> 4, a = (p >> 2) & 3, bb = p & 3; x = lv[a];   y = lv[bb];  tt = -1.f + 2.f * tm / 13.f; }
    else if (p < 88) { int q = p - 64; int tm = q >> 2, a = q & 3;    x = lv[a];   y = lv[a];   tt = -1.f + 2.f * (4 + tm) / 13.f; }
    else if (p < 94) { int q = p - 88; int tm = q / 3, a = q % 3;     x = lv[a];   y = lv[a+1]; tt = -1.f + 2.f * (10 + tm) / 13.f; }
    else             { int q = p - 94; int tm = q / 3, a = q % 3;     x = lv[a+1]; y = lv[a];   tt = -1.f + 2.f * (12 + tm) / 13.f; }
    float v = sinf(30.f * (x * sw0[t] + y * sw0[64 + t] + tt * sw0[128 + t] + sb0[t]));
    h[t] = v; __syncthreads();
    float v1 = sb1[t];
    for (int u = 0; u < 64; ++u) v1 += h[u] * sw1[u * 64 + t];
    v1 = sinf(v1);
    __syncthreads(); h[t] = v1; __syncthreads();
    float v2 = sb2[t];
    for (int u = 0; u < 64; ++u) v2 += h[u] * sw2[u * 64 + t];
    v2 = sinf(v2);
    __syncthreads(); h[t] = v2; __syncthreads();
    const float inv_fn = 0.06454972243679028f;  // 1/sqrt((2L+7)*C_IN) = 1/sqrt(240)
    for (int m = 0; m < 4; ++m) {
        int o = m * 64 + t;
        float vo = sbo[o];
        for (int u = 0; u < 64; ++u) vo += h[u] * swo[u * 256 + o];
        ws[p * 256 + o] = vo * inv_fn;
    }
}

// ---------------- bias sums: bsum[l][b][c] = sum_n bias_l[b,n,c] ----------------
__global__ __launch_bounds__(64) void reduce_b_kernel(
    const float4* __restrict__ b0, const float4* __restrict__ b1,
    const float4* __restrict__ b2, const float4* __restrict__ b3,
    float* __restrict__ ws) {
    const int z = blockIdx.x;  // l*16+b
    const int l = z >> 4, b = z & 15;
    const float4* bp = ((l == 0) ? b0 : (l == 1) ? b1 : (l == 2) ? b2 : b3) + (size_t)b * Nn * 4;
    const int lane = threadIdx.x;
    const int c4 = lane & 3, part = lane >> 2;
    float4 acc = make_float4(0.f, 0.f, 0.f, 0.f);
    for (int s = 0; s < 16; ++s) f4acc(acc, bp[(size_t)(part + s * 16) * 4 + c4]);
#pragma unroll
    for (int m = 4; m < 64; m <<= 1) {
        acc.x += __shfl_xor(acc.x, m); acc.y += __shfl_xor(acc.y, m);
        acc.z += __shfl_xor(acc.z, m); acc.w += __shfl_xor(acc.w, m);
    }
    if (lane < 4) {
        float* dst = ws + O_BS + (size_t)z * 16 + lane * 4;
        dst[0] = acc.x; dst[1] = acc.y; dst[2] = acc.z; dst[3] = acc.w;
    }
}

// -------- fused weight reduction: rsum (over j), csum (over k), allsum --------
__global__ __launch_bounds__(256) void reduce_w_kernel(
    const float4* __restrict__ w0, const float4* __restrict__ w1,
    const float4* __restrict__ w2, const float4* __restrict__ w3,
    float* __restrict__ ws, int bbase) {
    const int kchunk = blockIdx.x, jtile = blockIdx.y, z = blockIdx.z;
    const int l = z >> 2, b = bbase + (z & 3);
    const float4* __restrict__ w = (l == 0) ? w0 : (l == 1) ? w1 : (l == 2) ? w2 : w3;
    const int tid = threadIdx.x;
    const int c4 = tid & 3, jloc = tid >> 2;          // jloc 0..63
    const int j = jtile * 64 + jloc;
    const int lane = tid & 63, wave = tid >> 6;
    __shared__ float4 rpart[4][64][4];
    __shared__ float4 apart[4][4];
    const float4* wrow = w + (size_t)(b * Nn + j) * Nn * 4 + c4;
    const int kbase = kchunk * 64;
    float4 cacc = make_float4(0.f, 0.f, 0.f, 0.f);
#pragma unroll 8
    for (int kk = 0; kk < 64; ++kk) {
        float4 v = wrow[(size_t)(kbase + kk) * 4];
        f4acc(cacc, v);
        float4 r = v;
#pragma unroll
        for (int m = 4; m < 64; m <<= 1) {  // butterfly over the 16 j's in this wave
            r.x += __shfl_xor(r.x, m); r.y += __shfl_xor(r.y, m);
            r.z += __shfl_xor(r.z, m); r.w += __shfl_xor(r.w, m);
        }
        if (lane < 4) rpart[wave][kk][lane] = r;  // lane==c4, jj==0
    }
    float4 a = cacc;
#pragma unroll
    for (int m = 4; m < 64; m <<= 1) {
        a.x += __shfl_xor(a.x, m); a.y += __shfl_xor(a.y, m);
        a.z += __shfl_xor(a.z, m); a.w += __shfl_xor(a.w, m);
    }
    if (lane < 4) apart[wave][lane] = a;
    __syncthreads();
    // csum partial (this thread owns (j,c4), summed over its 64-k chunk)
    float* cdst = ws + O_CS + ((size_t)((l * 16 + b) * Nn + j)) * 16 + c4 * 4;
    atomicAdd(cdst + 0, cacc.x); atomicAdd(cdst + 1, cacc.y);
    atomicAdd(cdst + 2, cacc.z); atomicAdd(cdst + 3, cacc.w);
    // rsum partial: combine 4 waves for (kk2, c42)
    const int kk2 = tid >> 2, c42 = tid & 3;
    float4 s = rpart[0][kk2][c42];
    f4acc(s, rpart[1][kk2][c42]); f4acc(s, rpart[2][kk2][c42]); f4acc(s, rpart[3][kk2][c42]);
    float* rdst = ws + O_RS + ((size_t)((l * 16 + b) * Nn + kbase + kk2)) * 16 + c42 * 4;
    atomicAdd(rdst + 0, s.x); atomicAdd(rdst + 1, s.y);
    atomicAdd(rdst + 2, s.z); atomicAdd(rdst + 3, s.w);
    if (tid < 4) {
        float4 s2 = apart[0][tid];
        f4acc(s2, apart[1][tid]); f4acc(s2, apart[2][tid]); f4acc(s2, apart[3][tid]);
        float* adst = ws + O_AS + (size_t)(l * 16 + b) * 16 + tid * 4;
        atomicAdd(adst + 0, s2.x); atomicAdd(adst + 1, s2.y);
        atomicAdd(adst + 2, s2.z); atomicAdd(adst + 3, s2.w);
    }
}

// ------- assemble Arow/Bcol broadcast vectors + the ob outputs -------
__global__ __launch_bounds__(256) void vectors_kernel(
    const float* __restrict__ bias0, const float* __restrict__ bias1,
    const float* __restrict__ bias2, const float* __restrict__ bias3,
    float* __restrict__ ws, float* __restrict__ out, int bbase) {
    const int g = blockIdx.x * 256 + threadIdx.x;  // covers l(4) x bg(4) x n(256) x d(16)
    const int d = g & 15, n = (g >> 4) & 255, bg = (g >> 12) & 3, l = g >> 14;
    const int b = bbase + bg;
    const float invN = 1.f / 256.f, invNN = 1.f / 65536.f;
    const float* bias[4] = {bias0, bias1, bias2, bias3};
    const size_t rowi = (size_t)((l * 16 + b) * 256 + n) * 16;
    const float* cs = ws + O_CS + rowi;
    const float* rs = ws + O_RS + rowi;
    const float* bv = bias[l] + (size_t)(b * 256 + n) * 16;
    const float* dt = ws + T_DT;
    const float* Twrow  = dt + (0 * 4 + l) * 256;
    const float* Twcol  = dt + (1 * 4 + l) * 256;
    const float* Twb    = dt + (3 * 4 + l) * 256;
    const float* Tbwcol = dt + (4 * 4 + l) * 256;
    const float* Tbb    = dt + (5 * 4 + l) * 256;
    float arow = 0.f, bcol = 0.f, ob = 0.f;
#pragma unroll
    for (int c = 0; c < 16; ++c) {
        float cm = cs[c] * invN, rm = rs[c] * invN, bb = bv[c];
        arow += cm * Twcol[c * 16 + d];
        bcol += rm * Twrow[c * 16 + d] + bb * Twb[c * 16 + d];
        ob   += rm * Tbwcol[c * 16 + d] + bb * Tbb[c * 16 + d];
    }
    if (l > 0) {
        const float* rsm = ws + O_RS + (size_t)(((l - 1) * 16 + b) * 256 + n) * 16;
        const float* bvm = bias[l - 1] + (size_t)(b * 256 + n) * 16;
        const float* Twm1 = ws + T_M1 + (l - 1) * 256;
        const float* Tbm1 = ws + T_M1 + (3 + l - 1) * 256;
#pragma unroll
        for (int c = 0; c < 16; ++c)
            arow += rsm[c] * invN * Twm1[c * 16 + d] + bvm[c] * Tbm1[c * 16 + d];
    }
    if (l < 3) {
        const float* csp = ws + O_CS + (size_t)(((l + 1) * 16 + b) * 256 + n) * 16;
        const float* Twp1  = ws + T_P1 + l * 256;
        const float* Tbwp1 = ws + T_P1 + (3 + l) * 256;
#pragma unroll
        for (int c = 0; c < 16; ++c) {
            float cp = csp[c] * invN;
            bcol += cp * Twp1[c * 16 + d];
            ob   += cp * Tbwp1[c * 16 + d];
        }
    }
#pragma unroll
    for (int ll = 0; ll < 4; ++ll) {  // batch-global const terms
        const float* as_ = ws + O_AS + (size_t)(ll * 16 + b) * 16;
        const float* bs_ = ws + O_BS + (size_t)(ll * 16 + b) * 16;
        const float* g0 = ws + ((0 * 4 + l) * 4 + ll) * 256;
        const float* g1 = ws + ((1 * 4 + l) * 4 + ll) * 256;
        const float* g2 = ws + ((2 * 4 + l) * 4 + ll) * 256;
        const float* g3 = ws + ((3 * 4 + l) * 4 + ll) * 256;
#pragma unroll
        for (int c = 0; c < 16; ++c) {
            float am = as_[c] * invNN, bm = bs_[c] * invN;
            arow += am * g0[c * 16 + d] + bm * g1[c * 16 + d];
            ob   += am * g2[c * 16 + d] + bm * g3[c * 16 + d];
        }
    }
    ws[O_AROW + rowi + d] = arow;
    ws[O_BCOL + rowi + d] = bcol;
    out[(size_t)l * OSTRIDE + SZW + (size_t)(b * 256 + n) * 16 + d] = ob;
}

// ------- main transform: ow = w . T + Arow + Bcol -------
__global__ __launch_bounds__(256) void transform_kernel(
    const float4* __restrict__ w0, const float4* __restrict__ w1,
    const float4* __restrict__ w2, const float4* __restrict__ w3,
    const float* __restrict__ ws, float4* __restrict__ out, int bbase) {
    const int j = blockIdx.x, bg = blockIdx.y, l = blockIdx.z;
    const int b = bbase + bg;
    const float4* __restrict__ w = (l == 0) ? w0 : (l == 1) ? w1 : (l == 2) ? w2 : w3;
    const int tid = threadIdx.x;
    const int d4 = tid & 3, kk = tid >> 2;
    const float4* T4 = (const float4*)ws + (T_DT / 4) + (2 * 4 + l) * 64;  // t_w_w[l]
    float4 t[16];
#pragma unroll
    for (int c = 0; c < 16; ++c) t[c] = T4[c * 4 + d4];
    const size_t rowbase = (size_t)(b * 256 + j) * 256;
    const float4* Ar = (const float4*)(ws + O_AROW);
    const float4* Bc = (const float4*)(ws + O_BCOL) + (size_t)(l * 16 + b) * 256 * 4 + d4;
    const float4 arow = Ar[(size_t)((l * 16 + b) * 256 + j) * 4 + d4];
    const size_t outb = (size_t)l * (OSTRIDE / 4) + rowbase * 4 + d4;
#pragma unroll
    for (int s = 0; s < 4; ++s) {
        const int k = s * 64 + kk;
        float4 acc = f4add(arow, Bc[(size_t)k * 4]);
        const float4* wp = w + (rowbase + k) * 4;
        float4 v0 = wp[0], v1 = wp[1], v2 = wp[2], v3 = wp[3];
        f4fma(acc, v0.x, t[0]);  f4fma(acc, v0.y, t[1]);  f4fma(acc, v0.z, t[2]);  f4fma(acc, v0.w, t[3]);
        f4fma(acc, v1.x, t[4]);  f4fma(acc, v1.y, t[5]);  f4fma(acc, v1.z, t[6]);  f4fma(acc, v1.w, t[7]);
        f4fma(acc, v2.x, t[8]);  f4fma(acc, v2.y, t[9]);  f4fma(acc, v2.z, t[10]); f4fma(acc, v2.w, t[11]);
        f4fma(acc, v3.x, t[12]); f4fma(acc, v3.y, t[13]); f4fma(acc, v3.z, t[14]); f4fma(acc, v3.w, t[15]);
        out[outb + (size_t)k * 4] = acc;
    }
}

extern "C" void kernel_launch(void* const* d_in, const int* in_sizes, int n_in,
                              void* d_out, int out_size, void* d_ws, size_t ws_size,
                              hipStream_t stream) {
    const float *W[4], *Bv[4], *S[8];
    // setup_inputs() dict order is interleaved w0,b0,w1,b1,...; detect defensively.
    if (in_sizes[1] == in_sizes[0]) {  // grouped w0..w3,b0..b3
        for (int i = 0; i < 4; ++i) { W[i] = (const float*)d_in[i]; Bv[i] = (const float*)d_in[4 + i]; }
    } else {                           // interleaved
        for (int i = 0; i < 4; ++i) { W[i] = (const float*)d_in[2 * i]; Bv[i] = (const float*)d_in[2 * i + 1]; }
    }
    for (int k = 0; k < 8; ++k) S[k] = (const float*)d_in[8 + k];
    float* ws = (float*)d_ws;
    float* out = (float*)d_out;

    // zero the accumulator region (rsum, csum, allsum, bsum) — ws is 0xAA-poisoned
    hipMemsetAsync(ws + O_RS, 0, (size_t)(O_AROW - O_RS) * sizeof(float), stream);
    siren_kernel<<<100, 64, 0, stream>>>(S[0], S[1], S[2], S[3], S[4], S[5], S[6], S[7], ws);
    reduce_b_kernel<<<64, 64, 0, stream>>>((const float4*)Bv[0], (const float4*)Bv[1],
                                           (const float4*)Bv[2], (const float4*)Bv[3], ws);
    // batch-grouped schedule: the transform's re-read of each group's 64 MB of w
    // stays resident in the 256 MB Infinity Cache.
    for (int g = 0; g < 4; ++g) {
        const int bbase = 4 * g;
        reduce_w_kernel<<<dim3(4, 4, 16), 256, 0, stream>>>(
            (const float4*)W[0], (const float4*)W[1], (const float4*)W[2], (const float4*)W[3], ws, bbase);
        vectors_kernel<<<256, 256, 0, stream>>>(Bv[0], Bv[1], Bv[2], Bv[3], ws, out, bbase);
        transform_kernel<<<dim3(256, 4, 4), 256, 0, stream>>>(
            (const float4*)W[0], (const float4*)W[1], (const float4*)W[2], (const float4*)W[3],
            ws, (float4*)out, bbase);
    }
}

// Round 2
// 644.014 us; speedup vs baseline: 1.0954x; 1.0954x over previous
//
#include <hip/hip_runtime.h>
#include <math.h>

#define DEV_INLINE __device__ __forceinline__

constexpr int Nn = 256;
constexpr size_t SZW = (size_t)16 * 256 * 256 * 16;  // 16,777,216
constexpr size_t SZB = (size_t)16 * 256 * 16;        // 65,536
constexpr size_t OSTRIDE = SZW + SZB;                // per-layer output stride

// workspace layout (float offsets)
constexpr int T_GT = 0;          // global_terms [4][4][4][256]  = 16384
constexpr int T_DT = 16384;      // diag_terms   [6][4][256]     = 6144
constexpr int T_P1 = 22528;      // diag_p1      [2][3][256]     = 1536
constexpr int T_M1 = 24064;      // diag_m1      [2][3][256]     = 1536
constexpr int O_RS = 25600;      // rsum_raw [4][16][256][16]    = 262144
constexpr int O_CS = 287744;     // csum_raw                      = 262144
constexpr int O_AS = 549888;     // allsum_raw [4][16][16]        = 1024
constexpr int O_BS = 550912;     // bsum_raw   [4][16][16]        = 1024
constexpr int O_AROW = 551936;   // Arow [4][16][256][16]         = 262144
constexpr int O_BCOL = 814080;   // Bcol                          = 262144

DEV_INLINE void f4acc(float4& a, const float4 b) { a.x += b.x; a.y += b.y; a.z += b.z; a.w += b.w; }
DEV_INLINE float4 f4add(const float4 a, const float4 b) { return make_float4(a.x + b.x, a.y + b.y, a.z + b.z, a.w + b.w); }
DEV_INLINE void f4fma(float4& a, float s, const float4 t) {
    a.x = fmaf(s, t.x, a.x); a.y = fmaf(s, t.y, a.y);
    a.z = fmaf(s, t.z, a.z); a.w = fmaf(s, t.w, a.w);
}

// ---------------- SIREN: 100 points through 3->64->64->64->256 ----------------
__global__ __launch_bounds__(64) void siren_kernel(
    const float* __restrict__ sw0, const float* __restrict__ sb0,
    const float* __restrict__ sw1, const float* __restrict__ sb1,
    const float* __restrict__ sw2, const float* __restrict__ sb2,
    const float* __restrict__ swo, const float* __restrict__ sbo,
    float* __restrict__ ws) {
    __shared__ float h[64];
    const int p = blockIdx.x, t = threadIdx.x;
    const float lv[4] = {-1.f, -1.f / 3.f, 1.f / 3.f, 1.f};
    float x, y, tt;
    if (p < 64)      { int tm = p >> 4, a = (p >> 2) & 3, bb = p & 3; x = lv[a];   y = lv[bb];  tt = -1.f + 2.f * tm / 13.f; }
    else if (p < 88) { int q = p - 64; int tm = q >> 2, a = q & 3;    x = lv[a];   y = lv[a];   tt = -1.f + 2.f * (4 + tm) / 13.f; }
    else if (p < 94) { int q = p - 88; int tm = q / 3, a = q % 3;     x = lv[a];   y = lv[a+1]; tt = -1.f + 2.f * (10 + tm) / 13.f; }
    else             { int q = p - 94; int tm = q / 3, a = q % 3;     x = lv[a+1]; y = lv[a];   tt = -1.f + 2.f * (12 + tm) / 13.f; }
    float v = sinf(30.f * (x * sw0[t] + y * sw0[64 + t] + tt * sw0[128 + t] + sb0[t]));
    h[t] = v; __syncthreads();
    float v1 = sb1[t];
    for (int u = 0; u < 64; ++u) v1 += h[u] * sw1[u * 64 + t];
    v1 = sinf(v1);
    __syncthreads(); h[t] = v1; __syncthreads();
    float v2 = sb2[t];
    for (int u = 0; u < 64; ++u) v2 += h[u] * sw2[u * 64 + t];
    v2 = sinf(v2);
    __syncthreads(); h[t] = v2; __syncthreads();
    const float inv_fn = 0.06454972243679028f;  // 1/sqrt((2L+7)*C_IN) = 1/sqrt(240)
    for (int m = 0; m < 4; ++m) {
        int o = m * 64 + t;
        float vo = sbo[o];
        for (int u = 0; u < 64; ++u) vo += h[u] * swo[u * 256 + o];
        ws[p * 256 + o] = vo * inv_fn;
    }
}

// ---------------- bias sums: bsum[l][b][c] = sum_n bias_l[b,n,c] ----------------
__global__ __launch_bounds__(64) void reduce_b_kernel(
    const float4* __restrict__ b0, const float4* __restrict__ b1,
    const float4* __restrict__ b2, const float4* __restrict__ b3,
    float* __restrict__ ws) {
    const int z = blockIdx.x;  // l*16+b
    const int l = z >> 4, b = z & 15;
    const float4* bp = ((l == 0) ? b0 : (l == 1) ? b1 : (l == 2) ? b2 : b3) + (size_t)b * Nn * 4;
    const int lane = threadIdx.x;
    const int c4 = lane & 3, part = lane >> 2;
    float4 acc = make_float4(0.f, 0.f, 0.f, 0.f);
    for (int s = 0; s < 16; ++s) f4acc(acc, bp[(size_t)(part + s * 16) * 4 + c4]);
#pragma unroll
    for (int m = 4; m < 64; m <<= 1) {
        acc.x += __shfl_xor(acc.x, m); acc.y += __shfl_xor(acc.y, m);
        acc.z += __shfl_xor(acc.z, m); acc.w += __shfl_xor(acc.w, m);
    }
    if (lane < 4) {
        float* dst = ws + O_BS + (size_t)z * 16 + lane * 4;
        dst[0] = acc.x; dst[1] = acc.y; dst[2] = acc.z; dst[3] = acc.w;
    }
}

// -------- fused weight reduction via LDS tile: rsum, csum, allsum --------
// Tile = 32j x 32k x 16c = 64 KB. Load once (coalesced, XOR-swizzled), then
// reduce both directions from LDS with pure per-thread accumulation.
__global__ __launch_bounds__(256) void reduce_w_kernel(
    const float4* __restrict__ w0, const float4* __restrict__ w1,
    const float4* __restrict__ w2, const float4* __restrict__ w3,
    float* __restrict__ ws, int bbase) {
    const int tile = blockIdx.x;               // 64 tiles: kt(8) x jt(8)
    const int kt = tile & 7, jt = tile >> 3;
    const int lb = blockIdx.y;                 // 16: l*4 + bg
    const int l = lb >> 2, b = bbase + (lb & 3);
    const float4* __restrict__ w = (l == 0) ? w0 : (l == 1) ? w1 : (l == 2) ? w2 : w3;
    const int tid = threadIdx.x;

    __shared__ float4 lds4[4096];              // 32 rows x 128 float4 (64 KB)
    __shared__ float asumf[32][16];

    // ---- load slab: rows j = jt*32 .. +31, k = kt*32 .. +31, all 16 c ----
    const size_t base = ((size_t)(b * Nn + jt * 32)) * 1024 + (size_t)kt * 128;  // float4 units
#pragma unroll
    for (int it = 0; it < 16; ++it) {
        const int f = it * 256 + tid;          // 0..4095
        const int jl = f >> 7, idx = f & 127;  // 2 rows per iteration
        float4 v = w[base + (size_t)jl * 1024 + idx];
        lds4[jl * 128 + (idx ^ (jl & 7))] = v;
    }
    __syncthreads();

    const int h = tid & 1, c4 = (tid >> 1) & 3, loc = tid >> 3;  // loc: 0..31

    // ---- phase 1: csum[j][c] = sum over k (per-thread, h splits k-range) ----
    float4 acc = make_float4(0.f, 0.f, 0.f, 0.f);
#pragma unroll
    for (int q = 0; q < 16; ++q) {
        const int kk = h * 16 + q;
        f4acc(acc, lds4[loc * 128 + ((kk * 4 + c4) ^ (loc & 7))]);
    }
    acc.x += __shfl_xor(acc.x, 1); acc.y += __shfl_xor(acc.y, 1);
    acc.z += __shfl_xor(acc.z, 1); acc.w += __shfl_xor(acc.w, 1);
    if (h == 0) {
        float* cdst = ws + O_CS + ((size_t)((l * 16 + b) * Nn + jt * 32 + loc)) * 16 + c4 * 4;
        atomicAdd(cdst + 0, acc.x); atomicAdd(cdst + 1, acc.y);
        atomicAdd(cdst + 2, acc.z); atomicAdd(cdst + 3, acc.w);
    }

    // ---- phase 2: rsum[k][c] = sum over j (per-thread, h splits j-range) ----
    float4 acc2 = make_float4(0.f, 0.f, 0.f, 0.f);
#pragma unroll
    for (int q = 0; q < 16; ++q) {
        const int jj = h * 16 + q;
        f4acc(acc2, lds4[jj * 128 + ((loc * 4 + c4) ^ (jj & 7))]);
    }
    acc2.x += __shfl_xor(acc2.x, 1); acc2.y += __shfl_xor(acc2.y, 1);
    acc2.z += __shfl_xor(acc2.z, 1); acc2.w += __shfl_xor(acc2.w, 1);
    if (h == 0) {
        float* rdst = ws + O_RS + ((size_t)((l * 16 + b) * Nn + kt * 32 + loc)) * 16 + c4 * 4;
        atomicAdd(rdst + 0, acc2.x); atomicAdd(rdst + 1, acc2.y);
        atomicAdd(rdst + 2, acc2.z); atomicAdd(rdst + 3, acc2.w);
        asumf[loc][c4 * 4 + 0] = acc2.x; asumf[loc][c4 * 4 + 1] = acc2.y;
        asumf[loc][c4 * 4 + 2] = acc2.z; asumf[loc][c4 * 4 + 3] = acc2.w;
    }
    __syncthreads();

    // ---- allsum: block-reduce the rsum partials, one atomic per c ----
    if (tid < 16) {
        float s = 0.f;
#pragma unroll
        for (int kl = 0; kl < 32; ++kl) s += asumf[kl][tid];
        atomicAdd(ws + O_AS + (size_t)(l * 16 + b) * 16 + tid, s);
    }
}

// ------- assemble Arow/Bcol broadcast vectors + the ob outputs -------
__global__ __launch_bounds__(256) void vectors_kernel(
    const float* __restrict__ bias0, const float* __restrict__ bias1,
    const float* __restrict__ bias2, const float* __restrict__ bias3,
    float* __restrict__ ws, float* __restrict__ out, int bbase) {
    const int g = blockIdx.x * 256 + threadIdx.x;  // covers l(4) x bg(4) x n(256) x d(16)
    const int d = g & 15, n = (g >> 4) & 255, bg = (g >> 12) & 3, l = g >> 14;
    const int b = bbase + bg;
    const float invN = 1.f / 256.f, invNN = 1.f / 65536.f;
    const float* bias[4] = {bias0, bias1, bias2, bias3};
    const size_t rowi = (size_t)((l * 16 + b) * 256 + n) * 16;
    const float* cs = ws + O_CS + rowi;
    const float* rs = ws + O_RS + rowi;
    const float* bv = bias[l] + (size_t)(b * 256 + n) * 16;
    const float* dt = ws + T_DT;
    const float* Twrow  = dt + (0 * 4 + l) * 256;
    const float* Twcol  = dt + (1 * 4 + l) * 256;
    const float* Twb    = dt + (3 * 4 + l) * 256;
    const float* Tbwcol = dt + (4 * 4 + l) * 256;
    const float* Tbb    = dt + (5 * 4 + l) * 256;
    float arow = 0.f, bcol = 0.f, ob = 0.f;
#pragma unroll
    for (int c = 0; c < 16; ++c) {
        float cm = cs[c] * invN, rm = rs[c] * invN, bb = bv[c];
        arow += cm * Twcol[c * 16 + d];
        bcol += rm * Twrow[c * 16 + d] + bb * Twb[c * 16 + d];
        ob   += rm * Tbwcol[c * 16 + d] + bb * Tbb[c * 16 + d];
    }
    if (l > 0) {
        const float* rsm = ws + O_RS + (size_t)(((l - 1) * 16 + b) * 256 + n) * 16;
        const float* bvm = bias[l - 1] + (size_t)(b * 256 + n) * 16;
        const float* Twm1 = ws + T_M1 + (l - 1) * 256;
        const float* Tbm1 = ws + T_M1 + (3 + l - 1) * 256;
#pragma unroll
        for (int c = 0; c < 16; ++c)
            arow += rsm[c] * invN * Twm1[c * 16 + d] + bvm[c] * Tbm1[c * 16 + d];
    }
    if (l < 3) {
        const float* csp = ws + O_CS + (size_t)(((l + 1) * 16 + b) * 256 + n) * 16;
        const float* Twp1  = ws + T_P1 + l * 256;
        const float* Tbwp1 = ws + T_P1 + (3 + l) * 256;
#pragma unroll
        for (int c = 0; c < 16; ++c) {
            float cp = csp[c] * invN;
            bcol += cp * Twp1[c * 16 + d];
            ob   += cp * Tbwp1[c * 16 + d];
        }
    }
#pragma unroll
    for (int ll = 0; ll < 4; ++ll) {  // batch-global const terms
        const float* as_ = ws + O_AS + (size_t)(ll * 16 + b) * 16;
        const float* bs_ = ws + O_BS + (size_t)(ll * 16 + b) * 16;
        const float* g0 = ws + ((0 * 4 + l) * 4 + ll) * 256;
        const float* g1 = ws + ((1 * 4 + l) * 4 + ll) * 256;
        const float* g2 = ws + ((2 * 4 + l) * 4 + ll) * 256;
        const float* g3 = ws + ((3 * 4 + l) * 4 + ll) * 256;
#pragma unroll
        for (int c = 0; c < 16; ++c) {
            float am = as_[c] * invNN, bm = bs_[c] * invN;
            arow += am * g0[c * 16 + d] + bm * g1[c * 16 + d];
            ob   += am * g2[c * 16 + d] + bm * g3[c * 16 + d];
        }
    }
    ws[O_AROW + rowi + d] = arow;
    ws[O_BCOL + rowi + d] = bcol;
    out[(size_t)l * OSTRIDE + SZW + (size_t)(b * 256 + n) * 16 + d] = ob;
}

// ------- main transform: ow = w . T + Arow + Bcol -------
__global__ __launch_bounds__(256) void transform_kernel(
    const float4* __restrict__ w0, const float4* __restrict__ w1,
    const float4* __restrict__ w2, const float4* __restrict__ w3,
    const float* __restrict__ ws, float4* __restrict__ out, int bbase) {
    const int j = blockIdx.x, bg = blockIdx.y, l = blockIdx.z;
    const int b = bbase + bg;
    const float4* __restrict__ w = (l == 0) ? w0 : (l == 1) ? w1 : (l == 2) ? w2 : w3;
    const int tid = threadIdx.x;
    const int d4 = tid & 3, kk = tid >> 2;
    const float4* T4 = (const float4*)ws + (T_DT / 4) + (2 * 4 + l) * 64;  // t_w_w[l]
    float4 t[16];
#pragma unroll
    for (int c = 0; c < 16; ++c) t[c] = T4[c * 4 + d4];
    const size_t rowbase = (size_t)(b * 256 + j) * 256;
    const float4* Ar = (const float4*)(ws + O_AROW);
    const float4* Bc = (const float4*)(ws + O_BCOL) + (size_t)(l * 16 + b) * 256 * 4 + d4;
    const float4 arow = Ar[(size_t)((l * 16 + b) * 256 + j) * 4 + d4];
    const size_t outb = (size_t)l * (OSTRIDE / 4) + rowbase * 4 + d4;
#pragma unroll
    for (int s = 0; s < 4; ++s) {
        const int k = s * 64 + kk;
        float4 acc = f4add(arow, Bc[(size_t)k * 4]);
        const float4* wp = w + (rowbase + k) * 4;
        float4 v0 = wp[0], v1 = wp[1], v2 = wp[2], v3 = wp[3];
        f4fma(acc, v0.x, t[0]);  f4fma(acc, v0.y, t[1]);  f4fma(acc, v0.z, t[2]);  f4fma(acc, v0.w, t[3]);
        f4fma(acc, v1.x, t[4]);  f4fma(acc, v1.y, t[5]);  f4fma(acc, v1.z, t[6]);  f4fma(acc, v1.w, t[7]);
        f4fma(acc, v2.x, t[8]);  f4fma(acc, v2.y, t[9]);  f4fma(acc, v2.z, t[10]); f4fma(acc, v2.w, t[11]);
        f4fma(acc, v3.x, t[12]); f4fma(acc, v3.y, t[13]); f4fma(acc, v3.z, t[14]); f4fma(acc, v3.w, t[15]);
        out[outb + (size_t)k * 4] = acc;
    }
}

extern "C" void kernel_launch(void* const* d_in, const int* in_sizes, int n_in,
                              void* d_out, int out_size, void* d_ws, size_t ws_size,
                              hipStream_t stream) {
    const float *W[4], *Bv[4], *S[8];
    if (in_sizes[1] == in_sizes[0]) {  // grouped w0..w3,b0..b3
        for (int i = 0; i < 4; ++i) { W[i] = (const float*)d_in[i]; Bv[i] = (const float*)d_in[4 + i]; }
    } else {                           // interleaved
        for (int i = 0; i < 4; ++i) { W[i] = (const float*)d_in[2 * i]; Bv[i] = (const float*)d_in[2 * i + 1]; }
    }
    for (int k = 0; k < 8; ++k) S[k] = (const float*)d_in[8 + k];
    float* ws = (float*)d_ws;
    float* out = (float*)d_out;

    // zero the accumulator region (rsum, csum, allsum, bsum) — ws is 0xAA-poisoned
    hipMemsetAsync(ws + O_RS, 0, (size_t)(O_AROW - O_RS) * sizeof(float), stream);
    siren_kernel<<<100, 64, 0, stream>>>(S[0], S[1], S[2], S[3], S[4], S[5], S[6], S[7], ws);
    reduce_b_kernel<<<64, 64, 0, stream>>>((const float4*)Bv[0], (const float4*)Bv[1],
                                           (const float4*)Bv[2], (const float4*)Bv[3], ws);
    // batch-grouped schedule: the transform's re-read of each group's 64 MB of w
    // stays resident in the 256 MB Infinity Cache.
    for (int g = 0; g < 4; ++g) {
        const int bbase = 4 * g;
        reduce_w_kernel<<<dim3(64, 16), 256, 0, stream>>>(
            (const float4*)W[0], (const float4*)W[1], (const float4*)W[2], (const float4*)W[3], ws, bbase);
        vectors_kernel<<<256, 256, 0, stream>>>(Bv[0], Bv[1], Bv[2], Bv[3], ws, out, bbase);
        transform_kernel<<<dim3(256, 4, 4), 256, 0, stream>>>(
            (const float4*)W[0], (const float4*)W[1], (const float4*)W[2], (const float4*)W[3],
            ws, (float4*)out, bbase);
    }
}